// Round 7
// baseline (14.363 us; speedup 1.0000x reference)
//
#include <hip/hip_runtime.h>

typedef float float2v __attribute__((ext_vector_type(2)));

#define NB   8
#define CIN  3
#define HIN  128
#define WIN  128
#define OC   32
#define HO   126
#define WO   126
#define PAIRS (NB*HO*(WO/2))   // 63504 position-pairs (2 adjacent wo per thread)
#define KTOT 27
#define PACK 36                // 9 groups x {w0/2, w1/2, w2/2, (w0*w1*w2)/2}
#define OCPB 8                 // ocs per block (blockIdx.y selects chunk of 8)
#define OCSTRIDE (HO*WO)       // 15876

__device__ __forceinline__ float2v splat(float s) { return (float2v){s, s}; }

// Unscaled MAJ3 core: M = a+b+c - a*b*c  (true maj3 = M/2). 4 pk-ops.
__device__ __forceinline__ float2v majM(float2v a, float2v b, float2v c) {
    float2v t = a * b;
    float2v s = a + b + c;
    return __builtin_elementwise_fma(-t, c, s);
}

__global__ __launch_bounds__(256, 4)   // cap VGPR<=128 -> 4 waves/SIMD resident
void sconv2d_kernel(const float* __restrict__ x,
                    const float* __restrict__ w,
                    float* __restrict__ out) {
    // Per-block packed weights for this block's 8 ocs. Layout: [oc][group] ->
    // float4 {0.5*w(3g), 0.5*w(3g+1), 0.5*w(3g+2), 0.5*w(3g)*w(3g+1)*w(3g+2)}
    __shared__ __align__(16) float ws[OCPB * PACK];   // 1152 B
    {
        int ocbase = blockIdx.y * OCPB;
        for (int i = threadIdx.x; i < OCPB * PACK; i += 256) {
            int oc = i / PACK, r = i % PACK;
            int g = r / 4, j = r % 4;
            const float* wp = w + (ocbase + oc) * KTOT + 3 * g;
            float v = (j < 3) ? 0.5f * wp[j]
                              : 0.5f * wp[0] * wp[1] * wp[2];
            ws[i] = v;
        }
    }
    __syncthreads();

    int pp = blockIdx.x * 256 + threadIdx.x;
    if (pp >= PAIRS) return;
    int w2  = pp % (WO / 2);
    int t   = pp / (WO / 2);
    int ho  = t % HO;
    int n   = t / HO;
    int wo0 = 2 * w2;

    // Load the 2-position patch (9 rows x 4 floats) once; build pk pairs and
    // the oc-independent triple products Xg = {x0*x1*x2, x1*x2*x3}.
    float2v Av[9], Bv[9], Cv[9], Xg[9];
    #pragma unroll
    for (int r = 0; r < 9; ++r) {          // r = c*3 + kh
        int c = r / 3, kh = r % 3;
        const float* xr = x + (((n * CIN + c) * HIN) + ho + kh) * WIN + wo0;
        float2v P0 = *(const float2v*)xr;        // 8B aligned (wo0 even)
        float2v P1 = *(const float2v*)(xr + 2);
        float2v B  = __builtin_shufflevector(P0, P1, 1, 2);
        Av[r] = P0;
        Bv[r] = B;
        Cv[r] = P1;
        Xg[r] = P0 * B * P1;
    }

    int obase = ((n * OC + blockIdx.y * OCPB) * HO + ho) * WO + wo0;  // int32-safe

    #pragma unroll 2                     // bound live ranges (VGPR<=128)
    for (int i = 0; i < OCPB; ++i) {
        const float4* wg = (const float4*)&ws[i * PACK];  // wave-uniform -> broadcast
        float2v l1[9];
        #pragma unroll
        for (int g = 0; g < 9; ++g) {
            float4 q = wg[g];                // one ds_read_b128
            // l1 = 0.5*(x.w) - 0.5*Xg*W  == true level-1 maj3 (0.5 pre-folded in ws)
            float2v s = __builtin_elementwise_fma(Av[g], splat(q.x),
                        __builtin_elementwise_fma(Bv[g], splat(q.y),
                                                  Cv[g] * splat(q.z)));
            l1[g] = __builtin_elementwise_fma(-Xg[g], splat(q.w), s);
        }
        // Deferred-scale tree: level-2 unscaled M_j = s - abc (true m = M/2);
        // level-3: out = 0.5*(m0+m1+m2 - m0m1m2) = 0.25*sum(M) - 0.0625*prod(M)
        float2v M0 = majM(l1[0], l1[1], l1[2]);
        float2v M1 = majM(l1[3], l1[4], l1[5]);
        float2v M2 = majM(l1[6], l1[7], l1[8]);
        float2v S  = M0 + M1 + M2;
        float2v P  = M0 * M1 * M2;
        float2v res = __builtin_elementwise_fma(splat(0.25f), S,
                                                -0.0625f * P);

        // write-once streaming output: nontemporal dwordx2 store
        __builtin_nontemporal_store(res, (float2v*)(out + obase + i * OCSTRIDE));
    }
}

extern "C" void kernel_launch(void* const* d_in, const int* in_sizes, int n_in,
                              void* d_out, int out_size, void* d_ws, size_t ws_size,
                              hipStream_t stream) {
    const float* x = (const float*)d_in[0];
    const float* w = (const float*)d_in[1];
    float* out     = (float*)d_out;

    dim3 grid((PAIRS + 255) / 256, OC / OCPB);
    sconv2d_kernel<<<grid, 256, 0, stream>>>(x, w, out);
}